// Round 6
// baseline (289.271 us; speedup 1.0000x reference)
//
#include <hip/hip_runtime.h>
#include <hip/hip_cooperative_groups.h>

namespace cg = cooperative_groups;

constexpr int N_  = 64;
constexpr int C_  = 256;
constexpr int HW_ = 56 * 56;      // 3136
constexpr int NV_ = HW_ / 4;      // 784 f32x4 per slice
constexpr int G_  = 32;
constexpr int NC_ = N_ * C_;      // 16384
constexpr float EPS_ = 1e-5f;

typedef float f32x4 __attribute__((ext_vector_type(4)));

// 256 blocks x 512 threads (8 waves). Block b: n = b>>2, channels c0=(b&3)*64 .. +63.
// Wave w owns 8 slices nc = b*64 + w*8 + s. Lane covers vectors lane + 64k, k=0..11,
// lanes 0-15 also k=12. keep[s][0..4] stay in registers across the grid syncs.
__global__ __launch_bounds__(512, 2) void k_fused(
    const float* __restrict__ x,
    const float* __restrict__ fc_w,
    const float* __restrict__ fc_b,
    const float* __restrict__ weight,
    const float* __restrict__ bias,
    float* __restrict__ out,
    float* __restrict__ s1,
    float* __restrict__ s2,
    int*   __restrict__ gidxg)
{
    const int b    = blockIdx.x;
    const int t    = threadIdx.x;
    const int w    = t >> 6;
    const int lane = t & 63;
    const int n    = b >> 2;
    const int c0   = (b & 3) * 64;
    const int slice0 = b * 64 + w * 8;

    __shared__ float r1s[C_], r2s[C_];
    __shared__ int   gidxL[C_];
    __shared__ float mgs[G_], igs[G_];
    __shared__ float scs[64], shs[64];

    // ---------------- Phase 1: per-slice sums; keep k=0..4 in regs ----------------
    f32x4 keep[8][5];
    #pragma unroll
    for (int s = 0; s < 8; ++s) {
        const int nc = slice0 + s;
        const f32x4* xp = reinterpret_cast<const f32x4*>(x) + (size_t)nc * NV_;
        #pragma unroll
        for (int k = 0; k < 5; ++k) keep[s][k] = xp[lane + k * 64];
        f32x4 v5  = xp[lane + 320];
        f32x4 v6  = xp[lane + 384];
        f32x4 v7  = xp[lane + 448];
        f32x4 v8  = xp[lane + 512];
        f32x4 v9  = xp[lane + 576];
        f32x4 v10 = xp[lane + 640];
        f32x4 v11 = xp[lane + 704];
        const bool tail = lane < 16;
        f32x4 vt;
        if (tail) vt = xp[768 + lane];
        float a = 0.f, q = 0.f;
        #pragma unroll
        for (int k = 0; k < 5; ++k) {
            f32x4 v = keep[s][k];
            a += (v.x + v.y) + (v.z + v.w);
            q += (v.x * v.x + v.y * v.y) + (v.z * v.z + v.w * v.w);
        }
        a += (v5.x + v5.y) + (v5.z + v5.w);   q += (v5.x*v5.x + v5.y*v5.y) + (v5.z*v5.z + v5.w*v5.w);
        a += (v6.x + v6.y) + (v6.z + v6.w);   q += (v6.x*v6.x + v6.y*v6.y) + (v6.z*v6.z + v6.w*v6.w);
        a += (v7.x + v7.y) + (v7.z + v7.w);   q += (v7.x*v7.x + v7.y*v7.y) + (v7.z*v7.z + v7.w*v7.w);
        a += (v8.x + v8.y) + (v8.z + v8.w);   q += (v8.x*v8.x + v8.y*v8.y) + (v8.z*v8.z + v8.w*v8.w);
        a += (v9.x + v9.y) + (v9.z + v9.w);   q += (v9.x*v9.x + v9.y*v9.y) + (v9.z*v9.z + v9.w*v9.w);
        a += (v10.x + v10.y) + (v10.z + v10.w); q += (v10.x*v10.x + v10.y*v10.y) + (v10.z*v10.z + v10.w*v10.w);
        a += (v11.x + v11.y) + (v11.z + v11.w); q += (v11.x*v11.x + v11.y*v11.y) + (v11.z*v11.z + v11.w*v11.w);
        if (tail) {
            a += (vt.x + vt.y) + (vt.z + vt.w);
            q += (vt.x*vt.x + vt.y*vt.y) + (vt.z*vt.z + vt.w*vt.w);
        }
        #pragma unroll
        for (int off = 32; off; off >>= 1) {
            a += __shfl_down(a, off, 64);
            q += __shfl_down(q, off, 64);
        }
        if (lane == 0) {
            __hip_atomic_store(&s1[nc], a, __ATOMIC_RELAXED, __HIP_MEMORY_SCOPE_AGENT);
            __hip_atomic_store(&s2[nc], q, __ATOMIC_RELAXED, __HIP_MEMORY_SCOPE_AGENT);
        }
    }

    __threadfence();
    cg::this_grid().sync();

    // ---------------- Phase 2a: block b computes logits+argmax for channel c = b ----------------
    if (t < 64) {
        const int c = b;
        const int g = lane & 31, half = lane >> 5;
        const float inv_hw  = 1.f / (float)HW_;
        const float inv_hw1 = 1.f / (float)(HW_ - 1);
        const float* wg = fc_w + g * (2 * N_);
        float acc = half ? 0.f : fc_b[g];
        const int n0 = half * 32;
        #pragma unroll
        for (int nn = n0; nn < n0 + 32; ++nn) {
            const float a1 = __hip_atomic_load(&s1[nn * C_ + c], __ATOMIC_RELAXED, __HIP_MEMORY_SCOPE_AGENT);
            const float a2 = __hip_atomic_load(&s2[nn * C_ + c], __ATOMIC_RELAXED, __HIP_MEMORY_SCOPE_AGENT);
            const float m  = a1 * inv_hw;
            const float vr = (a2 - a1 * m) * inv_hw1;   // ddof=1
            acc += m * wg[nn] + vr * wg[N_ + nn];
        }
        acc += __shfl_down(acc, 32, 64);
        float bv = acc; int bi = g;
        #pragma unroll
        for (int off = 16; off; off >>= 1) {
            float ov = __shfl_down(bv, off, 32);
            int   oi = __shfl_down(bi, off, 32);
            if (ov > bv || (ov == bv && oi < bi)) { bv = ov; bi = oi; }
        }
        if (lane == 0)
            __hip_atomic_store(&gidxg[c], bi, __ATOMIC_RELAXED, __HIP_MEMORY_SCOPE_AGENT);
    }

    __threadfence();
    cg::this_grid().sync();

    // ---------------- Phase 2b: per-n group stats -> fused scale/shift (LDS) ----------------
    if (t < 256) {
        r1s[t]   = __hip_atomic_load(&s1[n * C_ + t], __ATOMIC_RELAXED, __HIP_MEMORY_SCOPE_AGENT);
        gidxL[t] = __hip_atomic_load(&gidxg[t],       __ATOMIC_RELAXED, __HIP_MEMORY_SCOPE_AGENT);
    } else {
        r2s[t - 256] = __hip_atomic_load(&s2[n * C_ + (t - 256)], __ATOMIC_RELAXED, __HIP_MEMORY_SCOPE_AGENT);
    }
    __syncthreads();
    if (t < G_) {
        float A = 0.f, B = 0.f; int k = 0;
        for (int cc = 0; cc < C_; ++cc)
            if (gidxL[cc] == t) { A += r1s[cc]; B += r2s[cc]; ++k; }
        const float cf = (float)k * (float)HW_;
        const float m  = A / fmaxf(cf, 1.f);
        const float vr = (B - A * m) / fmaxf(cf - 1.f, 1.f);
        mgs[t] = m;
        igs[t] = rsqrtf(vr + EPS_);
    }
    __syncthreads();
    if (t < 64) {
        const int c = c0 + t;
        const int g = gidxL[c];
        const float sc = igs[g] * weight[c];
        scs[t] = sc;
        shs[t] = bias[c] - mgs[g] * sc;
    }
    __syncthreads();

    // ---------------- Phase 3: normalize (regs + L3 re-read), NT stores ----------------
    #pragma unroll
    for (int s = 0; s < 8; ++s) {
        const int nc = slice0 + s;
        const float sc = scs[w * 8 + s];
        const float sh = shs[w * 8 + s];
        const f32x4* xp = reinterpret_cast<const f32x4*>(x)   + (size_t)nc * NV_;
        f32x4*       op = reinterpret_cast<f32x4*>(out)       + (size_t)nc * NV_;
        #pragma unroll
        for (int k = 0; k < 5; ++k)
            __builtin_nontemporal_store(keep[s][k] * sc + sh, op + lane + k * 64);
        #pragma unroll
        for (int k = 5; k < 12; ++k) {
            f32x4 v = xp[lane + k * 64];
            __builtin_nontemporal_store(v * sc + sh, op + lane + k * 64);
        }
        if (lane < 16) {
            f32x4 v = xp[768 + lane];
            __builtin_nontemporal_store(v * sc + sh, op + 768 + lane);
        }
    }
}

extern "C" void kernel_launch(void* const* d_in, const int* in_sizes, int n_in,
                              void* d_out, int out_size, void* d_ws, size_t ws_size,
                              hipStream_t stream) {
    const float* x      = (const float*)d_in[0];
    const float* fc_w   = (const float*)d_in[1];
    const float* fc_b   = (const float*)d_in[2];
    const float* weight = (const float*)d_in[3];
    const float* bias   = (const float*)d_in[4];
    float* outp = (float*)d_out;

    float* ws = (float*)d_ws;
    float* s1 = ws;
    float* s2 = ws + NC_;
    int*   gidxg = (int*)(ws + 2 * NC_);

    void* args[] = { (void*)&x, (void*)&fc_w, (void*)&fc_b, (void*)&weight, (void*)&bias,
                     (void*)&outp, (void*)&s1, (void*)&s2, (void*)&gidxg };
    hipLaunchCooperativeKernel((void*)k_fused, dim3(256), dim3(512), args, 0, stream);
}